// Round 1
// baseline (62558.990 us; speedup 1.0000x reference)
//
#include <hip/hip_runtime.h>
#include <stdint.h>

using u16 = unsigned short;
typedef __attribute__((ext_vector_type(8))) u16 u16x8;

__device__ __forceinline__ float bits2f(u16 u) {
    uint32_t x = ((uint32_t)u) << 16;
    return __builtin_bit_cast(float, x);
}
__device__ __forceinline__ u16 f2bits(float f) {
    uint32_t u = __builtin_bit_cast(uint32_t, f);
    u += 0x7FFFu + ((u >> 16) & 1u);
    return (u16)(u >> 16);
}
__device__ __forceinline__ float leaky(float v) { return v >= 0.f ? v : 0.01f * v; }

constexpr int N = 1024;

// Fused BinaryTreeConv + ChannelMixer for one layer.
// Computes yc[b,o,n] = sum_c,k g(b,c,n,k)*Wc[o,c,k] + bc[o]   (conv, pre-norm)
//          ym[b,o,n] = sum_c   x[b,c,n]*Wm[o,c]   + bm[o]     (mixer)
// plus per-workgroup partial (sum, sumsq) of yc for the tree-layernorm.
// Tile: OT x NT outputs per 256-thread block, TO x TN register micro-tile.
// LDS slots hold float4 {x[i0], x[i1], x[i2], x[n]} and {Wc0,Wc1,Wc2,Wm}.
template<bool BF16IN, int CI, int CO, int NT, int OT, int CK>
__global__ __launch_bounds__(256, 2) void conv_mix_kernel(
    const void* __restrict__ xin, const int* __restrict__ idx,
    const float* __restrict__ Wc, const float* __restrict__ bc,
    const float* __restrict__ Wm, const float* __restrict__ bm,
    u16* __restrict__ yc, u16* __restrict__ ym,
    float2* __restrict__ part)
{
    constexpr int TO = OT / 16, TN = NT / 16;
    constexpr int WROW = OT + OT / 8;            // skewed W row to dodge bank conflicts
    constexpr int XPT = CK * NT * 4 / 256;
    constexpr int WPT = CK * OT * 4 / 256;
    constexpr int NC = CI / CK;

    const int tid = threadIdx.x;
    const int n0 = blockIdx.x * NT;
    const int o0 = blockIdx.y * OT;
    const int b = blockIdx.z;

    __shared__ int4 sel[NT];
    __shared__ float4 XgT[CK][NT];
    __shared__ float4 WT[CK][WROW];
    __shared__ float redu[8];

    for (int n = tid; n < NT; n += 256) {
        const int* ip = idx + (size_t)b * 3 * N + 3 * (n0 + n);
        sel[n] = make_int4(ip[0], ip[1], ip[2], n0 + n);
    }
    __syncthreads();

    const u16* xb = (const u16*)xin + (size_t)b * CI * N;
    const float* xf = (const float*)xin + (size_t)b * CI * N;

    float xr[XPT], wr[WPT];

    auto load_x = [&](int c0, float* dst) {
        #pragma unroll
        for (int rr = 0; rr < XPT; ++rr) {
            int s = tid + 256 * rr;
            int c = s / (NT * 4);
            int n = (s >> 2) % NT;
            int k = s & 3;
            int4 sl = sel[n];
            int sn = (k == 0) ? sl.x : (k == 1) ? sl.y : (k == 2) ? sl.z : sl.w;
            size_t off = (size_t)(c0 + c) * N + sn;
            if constexpr (BF16IN) dst[rr] = bits2f(xb[off]);
            else                  dst[rr] = xf[off];
        }
    };
    auto load_w = [&](int c0, float* dst) {
        #pragma unroll
        for (int rr = 0; rr < WPT; ++rr) {
            int s = tid + 256 * rr;
            int c = s / (OT * 4);
            int o = (s >> 2) % OT;
            int k = s & 3;
            dst[rr] = (k < 3) ? Wc[((size_t)(o0 + o) * CI + (c0 + c)) * 3 + k]
                              : Wm[(size_t)(o0 + o) * CI + (c0 + c)];
        }
    };

    float accc[TO][TN] = {};
    float accm[TO][TN] = {};
    const int og = tid >> 4, nl = tid & 15;

    load_x(0, xr);
    load_w(0, wr);

    for (int ic = 0; ic < NC; ++ic) {
        __syncthreads();
        #pragma unroll
        for (int rr = 0; rr < XPT; ++rr) {
            int s = tid + 256 * rr;
            int c = s / (NT * 4); int n = (s >> 2) % NT; int k = s & 3;
            ((float*)&XgT[c][n])[k] = xr[rr];
        }
        #pragma unroll
        for (int rr = 0; rr < WPT; ++rr) {
            int s = tid + 256 * rr;
            int c = s / (OT * 4); int o = (s >> 2) % OT; int k = s & 3;
            ((float*)&WT[c][o + (o >> 3)])[k] = wr[rr];
        }
        __syncthreads();
        if (ic + 1 < NC) { load_x((ic + 1) * CK, xr); load_w((ic + 1) * CK, wr); }
        #pragma unroll
        for (int cc = 0; cc < CK; ++cc) {
            float4 xg[TN], w[TO];
            #pragma unroll
            for (int i = 0; i < TN; ++i) xg[i] = XgT[cc][nl + 16 * i];
            #pragma unroll
            for (int j = 0; j < TO; ++j) { int o = og * TO + j; w[j] = WT[cc][o + (o >> 3)]; }
            #pragma unroll
            for (int j = 0; j < TO; ++j)
                #pragma unroll
                for (int i = 0; i < TN; ++i) {
                    accc[j][i] += w[j].x * xg[i].x;
                    accc[j][i] += w[j].y * xg[i].y;
                    accc[j][i] += w[j].z * xg[i].z;
                    accm[j][i] += w[j].w * xg[i].w;
                }
        }
    }

    float s1 = 0.f, s2 = 0.f;
    #pragma unroll
    for (int j = 0; j < TO; ++j) {
        int o = o0 + og * TO + j;
        float bcv = bc[o], bmv = bm[o];
        size_t rowoff = ((size_t)b * CO + o) * N + n0;
        #pragma unroll
        for (int i = 0; i < TN; ++i) {
            int nloc = nl + 16 * i;
            float vc = accc[j][i] + bcv;
            float vm = accm[j][i] + bmv;
            yc[rowoff + nloc] = f2bits(vc);
            ym[rowoff + nloc] = f2bits(vm);
            s1 += vc;
            s2 += vc * vc;
        }
    }
    #pragma unroll
    for (int m = 32; m; m >>= 1) { s1 += __shfl_xor(s1, m); s2 += __shfl_xor(s2, m); }
    if ((tid & 63) == 0) { redu[(tid >> 6) * 2] = s1; redu[(tid >> 6) * 2 + 1] = s2; }
    __syncthreads();
    if (tid == 0) {
        float t1 = redu[0] + redu[2] + redu[4] + redu[6];
        float t2 = redu[1] + redu[3] + redu[5] + redu[7];
        int nwg = gridDim.x * gridDim.y;
        int wg = blockIdx.x + gridDim.x * blockIdx.y;
        part[(size_t)b * nwg + wg] = make_float2(t1, t2);
    }
}

__global__ __launch_bounds__(64) void reduce_stats_kernel(
    const float2* __restrict__ part, float2* __restrict__ stats, int nparts, float Mf)
{
    int b = blockIdx.x;
    float s1 = 0.f, s2 = 0.f;
    for (int i = threadIdx.x; i < nparts; i += 64) {
        float2 p = part[(size_t)b * nparts + i];
        s1 += p.x; s2 += p.y;
    }
    #pragma unroll
    for (int m = 32; m; m >>= 1) { s1 += __shfl_xor(s1, m); s2 += __shfl_xor(s2, m); }
    if (threadIdx.x == 0) {
        float mu = s1 / Mf;
        float var = (s2 - s1 * s1 / Mf) / (Mf - 1.f);   // ddof = 1
        var = fmaxf(var, 0.f);
        stats[b] = make_float2(mu, 1.f / (sqrtf(var) + 1e-5f));
    }
}

// x = leaky(ym + (yc - mu) * inv), written in place over yc (bf16).
__global__ __launch_bounds__(256) void norm_kernel(
    u16* __restrict__ yc, const u16* __restrict__ ym,
    const float2* __restrict__ stats, int perb)
{
    size_t e = ((size_t)blockIdx.x * 256 + threadIdx.x) * 8;
    int b = (int)(e / (size_t)perb);
    float2 st = stats[b];
    u16x8 vc = *(const u16x8*)(yc + e);
    u16x8 vm = *(const u16x8*)(ym + e);
    u16x8 r;
    #pragma unroll
    for (int i = 0; i < 8; ++i) {
        float v = bits2f(vm[i]) + (bits2f(vc[i]) - st.x) * st.y;
        r[i] = f2bits(leaky(v));
    }
    *(u16x8*)(yc + e) = r;
}

// Fused: normalize layer-3 output on the fly, masked max-pool over valid nodes,
// then the 64->32->1 MLP. One workgroup per batch element.
__global__ __launch_bounds__(256) void final_kernel(
    const u16* __restrict__ yc3, const u16* __restrict__ ym3,
    const float2* __restrict__ stats, const int* __restrict__ nodes,
    const float* __restrict__ W1, const float* __restrict__ b1,
    const float* __restrict__ W2, const float* __restrict__ b2,
    float* __restrict__ out)
{
    int b = blockIdx.x;
    int tid = threadIdx.x;
    float2 st = stats[b];
    int nv = nodes[b];
    int o = tid >> 2, ln = tid & 3;
    const u16* pc = yc3 + ((size_t)b * 64 + o) * N;
    const u16* pm = ym3 + ((size_t)b * 64 + o) * N;
    float mx = -__builtin_inff();
    for (int kc = ln; kc < N / 8; kc += 4) {
        int base = kc * 8;
        if (base >= nv) continue;
        u16x8 vc = *(const u16x8*)(pc + base);
        u16x8 vm = *(const u16x8*)(pm + base);
        #pragma unroll
        for (int ii = 0; ii < 8; ++ii) {
            if (base + ii < nv) {
                float v = leaky(bits2f(vm[ii]) + (bits2f(vc[ii]) - st.x) * st.y);
                mx = fmaxf(mx, v);
            }
        }
    }
    mx = fmaxf(mx, __shfl_xor(mx, 1));
    mx = fmaxf(mx, __shfl_xor(mx, 2));
    __shared__ float pooled[64];
    __shared__ float hbuf[32];
    if (ln == 0) pooled[o] = mx;
    __syncthreads();
    if (tid < 32) {
        float h = b1[tid];
        #pragma unroll 8
        for (int oo = 0; oo < 64; ++oo) h += pooled[oo] * W1[oo * 32 + tid];
        hbuf[tid] = leaky(h);
    }
    __syncthreads();
    if (tid == 0) {
        float r = b2[0];
        for (int j = 0; j < 32; ++j) r += hbuf[j] * W2[j];
        out[b] = r;
    }
}

extern "C" void kernel_launch(void* const* d_in, const int* in_sizes, int n_in,
                              void* d_out, int out_size, void* d_ws, size_t ws_size,
                              hipStream_t stream)
{
    (void)in_sizes; (void)n_in; (void)out_size; (void)ws_size;
    const float* trees = (const float*)d_in[0];
    const int* indexes = (const int*)d_in[1];
    const int* nodes   = (const int*)d_in[2];
    const float* Wc1 = (const float*)d_in[3];
    const float* bc1 = (const float*)d_in[4];
    const float* Wm1 = (const float*)d_in[5];
    const float* bm1 = (const float*)d_in[6];
    const float* Wc2 = (const float*)d_in[7];
    const float* bc2 = (const float*)d_in[8];
    const float* Wm2 = (const float*)d_in[9];
    const float* bm2 = (const float*)d_in[10];
    const float* Wc3 = (const float*)d_in[11];
    const float* bc3 = (const float*)d_in[12];
    const float* Wm3 = (const float*)d_in[13];
    const float* bm3 = (const float*)d_in[14];
    const float* W1 = (const float*)d_in[15];
    const float* b1 = (const float*)d_in[16];
    const float* W2 = (const float*)d_in[17];
    const float* b2 = (const float*)d_in[18];
    float* out = (float*)d_out;

    // ws layout (bytes):
    //   A : [0, 128 MiB)               region A (bf16)
    //   B : [128 MiB, 256 MiB)         region B (bf16)
    //   partials (3 x 256*64 float2), stats (3 x 256 float2)
    char* ws = (char*)d_ws;
    u16* A  = (u16*)ws;
    u16* Bb = (u16*)(ws + (size_t)134217728);
    float2* part1 = (float2*)(ws + (size_t)268435456);
    float2* part2 = part1 + 256 * 64;
    float2* part3 = part2 + 256 * 64;
    float2* stats1 = part3 + 256 * 64;
    float2* stats2 = stats1 + 256;
    float2* stats3 = stats2 + 256;

    dim3 blk(256);

    // Layer 1: 160 -> 256, fp32 input (trees). yc1 -> A, ym1 -> B.
    conv_mix_kernel<false, 160, 256, 128, 128, 8><<<dim3(8, 2, 256), blk, 0, stream>>>(
        trees, indexes, Wc1, bc1, Wm1, bm1, A, Bb, part1);
    reduce_stats_kernel<<<dim3(256), dim3(64), 0, stream>>>(part1, stats1, 16, 262144.f);
    norm_kernel<<<dim3(32768), blk, 0, stream>>>(A, Bb, stats1, 262144);   // x1 in A

    // Layer 2: 256 -> 128. yc2 -> B[0:], ym2 -> B[33554432:].
    conv_mix_kernel<true, 256, 128, 128, 128, 8><<<dim3(8, 1, 256), blk, 0, stream>>>(
        A, indexes, Wc2, bc2, Wm2, bm2, Bb, Bb + 33554432, part2);
    reduce_stats_kernel<<<dim3(256), dim3(64), 0, stream>>>(part2, stats2, 8, 131072.f);
    norm_kernel<<<dim3(16384), blk, 0, stream>>>(Bb, Bb + 33554432, stats2, 131072); // x2 in B

    // Layer 3: 128 -> 64. yc3 -> A[0:], ym3 -> A[16777216:].
    conv_mix_kernel<true, 128, 64, 64, 64, 16><<<dim3(16, 1, 256), blk, 0, stream>>>(
        Bb, indexes, Wc3, bc3, Wm3, bm3, A, A + 16777216, part3);
    reduce_stats_kernel<<<dim3(256), dim3(64), 0, stream>>>(part3, stats3, 16, 65536.f);

    // Fused norm3 + masked max-pool + MLP.
    final_kernel<<<dim3(256), blk, 0, stream>>>(A, A + 16777216, stats3, nodes,
                                                W1, b1, W2, b2, out);
}

// Round 2
// 581.936 us; speedup vs baseline: 107.5015x; 107.5015x over previous
//
#include <hip/hip_runtime.h>
#include <stdint.h>

using f16 = _Float16;
typedef __attribute__((ext_vector_type(8))) f16 f16x8;
typedef __attribute__((ext_vector_type(4))) float f32x4;

constexpr int N = 1024;

__device__ __forceinline__ float leaky(float v) { return v >= 0.f ? v : 0.01f * v; }

__device__ __forceinline__ void dma16(const void* g, void* l) {
    __builtin_amdgcn_global_load_lds(
        (const __attribute__((address_space(1))) uint32_t*)g,
        (__attribute__((address_space(3))) uint32_t*)l, 16, 0, 0);
}

// ---------------------------------------------------------------------------
// Phase A: BinaryTreeConv  Yc^T[n][o] = sum_k Xg[n][kap] * Wfc[kap][o] + bc
// Tile: 64 nodes x CO, 4 waves (2 n-groups x 2 o-groups), K chunks of 32.
// LDS: double-buffered [64 n][32 kap] f16 tile, XOR-swizzled rows, filled by
// global_load_lds with inverse-swizzled per-lane gather sources.
// ---------------------------------------------------------------------------
template<int CI, int CO>
__global__ __launch_bounds__(256) void convA_kernel(
    const f16* __restrict__ X, const int* __restrict__ idx,
    const f16* __restrict__ Wf, const float* __restrict__ bc,
    f16* __restrict__ yc, float2* __restrict__ part)
{
    constexpr int T = 3 * CI / 32;      // K chunks
    constexpr int UW = CO / 32;         // o-subtiles per wave
    constexpr int U = CO / 16;          // o-subtiles total

    __shared__ alignas(16) f16 stage[2][2048];   // 2 x 4KB
    __shared__ float redu[8];

    const int tid = threadIdx.x;
    const int w = tid >> 6, l = tid & 63;
    const int wn = w & 1, wo = w >> 1;
    const int n0 = blockIdx.x * 64;
    const int b = blockIdx.y;

    // inverse-swizzle: which (n, 16B-granule g) this thread's DMA lane fills
    const int G = tid;
    const int nloc = (((G >> 2) ^ (G >> 4)) & 1) | (((G >> 3) & 1) << 1)
                   | (((G >> 4) & 1) << 2) | ((G >> 5) << 3);
    const int g = ((G ^ (G >> 2) ^ (G >> 4)) & 1) | ((((G >> 1) ^ (G >> 3)) & 1) << 1);

    const int* ip = idx + (size_t)b * 3 * N + 3 * (n0 + nloc);
    const size_t xb = (size_t)b * N * CI;
    const char* s0 = (const char*)(X + xb + (size_t)ip[0] * CI) + g * 16;
    const char* s1 = (const char*)(X + xb + (size_t)ip[1] * CI) + g * 16;
    const char* s2 = (const char*)(X + xb + (size_t)ip[2] * CI) + g * 16;

    char* sbase = (char*)&stage[0][0];
    char* mydst = sbase + w * 1024;

    // A-fragment read offsets (swizzled)
    int abyte[2];
    #pragma unroll
    for (int rt = 0; rt < 2; ++rt) {
        int nl_ = 32 * wn + 16 * rt + (l & 15);
        abyte[rt] = (nl_ * 64 + 16 * (l >> 4)) ^ ((nl_ & 7) << 4);
    }

    f32x4 acc[2][UW] = {};

    dma16(s0, mydst);                  // chunk 0: seg 0, c0 = 0
    __syncthreads();

    for (int t = 0; t < T; ++t) {
        const char* sb = sbase + (t & 1) * 4096;
        if (t + 1 < T) {
            int kk = 32 * (t + 1);
            const char* sp = (kk < CI) ? s0 + (size_t)kk * 2
                           : (kk < 2 * CI) ? s1 + (size_t)(kk - CI) * 2
                           : s2 + (size_t)(kk - 2 * CI) * 2;
            dma16(sp, mydst + ((t + 1) & 1) * 4096);
        }
        f16x8 a0 = *(const f16x8*)(sb + abyte[0]);
        f16x8 a1 = *(const f16x8*)(sb + abyte[1]);
        #pragma unroll
        for (int uu = 0; uu < UW; ++uu) {
            const int ug = wo * UW + uu;
            f16x8 wv = *(const f16x8*)(Wf + (((size_t)t * U + ug) * 64 + l) * 8);
            acc[0][uu] = __builtin_amdgcn_mfma_f32_16x16x32_f16(a0, wv, acc[0][uu], 0, 0, 0);
            acc[1][uu] = __builtin_amdgcn_mfma_f32_16x16x32_f16(a1, wv, acc[1][uu], 0, 0, 0);
        }
        __syncthreads();
    }

    // epilogue: bias, store f16, per-tree stats partials
    float p1 = 0.f, p2 = 0.f;
    #pragma unroll
    for (int rt = 0; rt < 2; ++rt) {
        #pragma unroll
        for (int uu = 0; uu < UW; ++uu) {
            int o = wo * (CO / 2) + uu * 16 + (l & 15);
            float bcv = bc[o];
            size_t rb = ((size_t)b * N + (n0 + 32 * wn + 16 * rt + 4 * (l >> 4))) * CO + o;
            #pragma unroll
            for (int j = 0; j < 4; ++j) {
                float v = acc[rt][uu][j] + bcv;
                yc[rb + (size_t)j * CO] = (f16)v;
                p1 += v; p2 += v * v;
            }
        }
    }
    #pragma unroll
    for (int m = 32; m; m >>= 1) { p1 += __shfl_xor(p1, m); p2 += __shfl_xor(p2, m); }
    if (l == 0) { redu[w * 2] = p1; redu[w * 2 + 1] = p2; }
    __syncthreads();
    if (tid == 0)
        part[(size_t)b * 16 + blockIdx.x] =
            make_float2(redu[0] + redu[2] + redu[4] + redu[6],
                        redu[1] + redu[3] + redu[5] + redu[7]);
}

__global__ __launch_bounds__(64) void reduce_stats_kernel(
    const float2* __restrict__ part, float2* __restrict__ stats, int nparts, float Mf)
{
    int b = blockIdx.x;
    float s1 = 0.f, s2 = 0.f;
    for (int i = threadIdx.x; i < nparts; i += 64) {
        float2 p = part[(size_t)b * nparts + i];
        s1 += p.x; s2 += p.y;
    }
    #pragma unroll
    for (int m = 32; m; m >>= 1) { s1 += __shfl_xor(s1, m); s2 += __shfl_xor(s2, m); }
    if (threadIdx.x == 0) {
        float mu = s1 / Mf;
        float var = (s2 - s1 * s1 / Mf) / (Mf - 1.f);   // ddof = 1
        var = fmaxf(var, 0.f);
        stats[b] = make_float2(mu, 1.f / (sqrtf(var) + 1e-5f));
    }
}

// ---------------------------------------------------------------------------
// Phase B: ChannelMixer GEMM (K = CI, identity rows, no gather) with the
// TreeLayerNorm + leaky fused into the epilogue:  x = leaky(ym + (yc-mu)*inv)
// written in place over yc.
// ---------------------------------------------------------------------------
template<int CI, int CO>
__global__ __launch_bounds__(256) void mixB_kernel(
    const f16* __restrict__ X, const f16* __restrict__ Wf, const float* __restrict__ bm,
    f16* __restrict__ y, const float2* __restrict__ stats)
{
    constexpr int T = CI / 32;
    constexpr int UW = CO / 32;
    constexpr int U = CO / 16;

    __shared__ alignas(16) f16 stage[2][2048];

    const int tid = threadIdx.x;
    const int w = tid >> 6, l = tid & 63;
    const int wn = w & 1, wo = w >> 1;
    const int n0 = blockIdx.x * 64;
    const int b = blockIdx.y;

    const int G = tid;
    const int nloc = (((G >> 2) ^ (G >> 4)) & 1) | (((G >> 3) & 1) << 1)
                   | (((G >> 4) & 1) << 2) | ((G >> 5) << 3);
    const int g = ((G ^ (G >> 2) ^ (G >> 4)) & 1) | ((((G >> 1) ^ (G >> 3)) & 1) << 1);

    const size_t xb = (size_t)b * N * CI;
    const char* s0 = (const char*)(X + xb + (size_t)(n0 + nloc) * CI) + g * 16;

    char* sbase = (char*)&stage[0][0];
    char* mydst = sbase + w * 1024;

    int abyte[2];
    #pragma unroll
    for (int rt = 0; rt < 2; ++rt) {
        int nl_ = 32 * wn + 16 * rt + (l & 15);
        abyte[rt] = (nl_ * 64 + 16 * (l >> 4)) ^ ((nl_ & 7) << 4);
    }

    f32x4 acc[2][UW] = {};

    dma16(s0, mydst);
    __syncthreads();

    for (int t = 0; t < T; ++t) {
        const char* sb = sbase + (t & 1) * 4096;
        if (t + 1 < T) dma16(s0 + (size_t)(t + 1) * 64, mydst + ((t + 1) & 1) * 4096);
        f16x8 a0 = *(const f16x8*)(sb + abyte[0]);
        f16x8 a1 = *(const f16x8*)(sb + abyte[1]);
        #pragma unroll
        for (int uu = 0; uu < UW; ++uu) {
            const int ug = wo * UW + uu;
            f16x8 wv = *(const f16x8*)(Wf + (((size_t)t * U + ug) * 64 + l) * 8);
            acc[0][uu] = __builtin_amdgcn_mfma_f32_16x16x32_f16(a0, wv, acc[0][uu], 0, 0, 0);
            acc[1][uu] = __builtin_amdgcn_mfma_f32_16x16x32_f16(a1, wv, acc[1][uu], 0, 0, 0);
        }
        __syncthreads();
    }

    const float2 st = stats[b];
    #pragma unroll
    for (int rt = 0; rt < 2; ++rt) {
        #pragma unroll
        for (int uu = 0; uu < UW; ++uu) {
            int o = wo * (CO / 2) + uu * 16 + (l & 15);
            float bmv = bm[o];
            size_t rb = ((size_t)b * N + (n0 + 32 * wn + 16 * rt + 4 * (l >> 4))) * CO + o;
            #pragma unroll
            for (int j = 0; j < 4; ++j) {
                size_t off = rb + (size_t)j * CO;
                float ycv = (float)y[off];
                float v = acc[rt][uu][j] + bmv + (ycv - st.x) * st.y;
                y[off] = (f16)leaky(v);
            }
        }
    }
}

// fp32 [B][160][N] -> f16 [B][N][160]
__global__ __launch_bounds__(256) void transpose_kernel(
    const float* __restrict__ trees, f16* __restrict__ X0)
{
    __shared__ f16 tile[32][66];
    int b = blockIdx.z, c0 = blockIdx.y * 32, n0 = blockIdx.x * 64;
    int tid = threadIdx.x;
    int nl = tid & 63, c4 = tid >> 6;
    #pragma unroll
    for (int cc = 0; cc < 8; ++cc) {
        int c = c4 * 8 + cc;
        tile[c][nl] = (f16)trees[((size_t)b * 160 + c0 + c) * N + n0 + nl];
    }
    __syncthreads();
    int nn = tid >> 2, gc = tid & 3;
    f16x8 pack;
    #pragma unroll
    for (int e = 0; e < 8; ++e) pack[e] = tile[gc * 8 + e][nn];
    *(f16x8*)(X0 + ((size_t)b * N + n0 + nn) * 160 + c0 + gc * 8) = pack;
}

// weights -> fragment-ready f16 layout: elem ((t*U+u)*64+l)*8+j  holds
// W[kap = 32t+8*(l>>4)+j][o = 16u+(l&15)], kappa-order kap = k*CI + c.
__global__ __launch_bounds__(256) void prepW_kernel(
    const float* __restrict__ Wsrc, f16* __restrict__ out,
    int K, int CO, int CI, int isconv)
{
    int e = blockIdx.x * 256 + threadIdx.x;
    if (e >= K * CO) return;
    int j = e & 7, l = (e >> 3) & 63, r = e >> 9;
    int U = CO / 16;
    int u = r % U, t = r / U;
    int kap = 32 * t + 8 * (l >> 4) + j;
    int o = 16 * u + (l & 15);
    float v = isconv ? Wsrc[((size_t)o * CI + (kap % CI)) * 3 + kap / CI]
                     : Wsrc[(size_t)o * CI + kap];
    out[e] = (f16)v;
}

// masked max-pool over valid nodes + 64->32->1 MLP; x3 is [b][n][64] f16.
__global__ __launch_bounds__(256) void final_kernel(
    const f16* __restrict__ x3, const int* __restrict__ nodes,
    const float* __restrict__ W1, const float* __restrict__ b1,
    const float* __restrict__ W2, const float* __restrict__ b2,
    float* __restrict__ out)
{
    int b = blockIdx.x, tid = threadIdx.x;
    int o = tid & 63, r = tid >> 6;
    int nv = nodes[b];
    const f16* p = x3 + (size_t)b * N * 64 + o;
    float mx = -3.4e38f;
    for (int n = r; n < nv; n += 4) mx = fmaxf(mx, (float)p[(size_t)n * 64]);
    __shared__ float pool[4][64];
    __shared__ float pooled[64], hbuf[32];
    pool[r][o] = mx;
    __syncthreads();
    if (tid < 64) pooled[tid] = fmaxf(fmaxf(pool[0][tid], pool[1][tid]),
                                      fmaxf(pool[2][tid], pool[3][tid]));
    __syncthreads();
    if (tid < 32) {
        float h = b1[tid];
        #pragma unroll 8
        for (int oo = 0; oo < 64; ++oo) h += pooled[oo] * W1[oo * 32 + tid];
        hbuf[tid] = leaky(h);
    }
    __syncthreads();
    if (tid == 0) {
        float rr = b2[0];
        for (int jj = 0; jj < 32; ++jj) rr += hbuf[jj] * W2[jj];
        out[b] = rr;
    }
}

extern "C" void kernel_launch(void* const* d_in, const int* in_sizes, int n_in,
                              void* d_out, int out_size, void* d_ws, size_t ws_size,
                              hipStream_t stream)
{
    (void)in_sizes; (void)n_in; (void)out_size; (void)ws_size;
    const float* trees = (const float*)d_in[0];
    const int* indexes = (const int*)d_in[1];
    const int* nodes   = (const int*)d_in[2];
    const float* Wc1 = (const float*)d_in[3];
    const float* bc1 = (const float*)d_in[4];
    const float* Wm1 = (const float*)d_in[5];
    const float* bm1 = (const float*)d_in[6];
    const float* Wc2 = (const float*)d_in[7];
    const float* bc2 = (const float*)d_in[8];
    const float* Wm2 = (const float*)d_in[9];
    const float* bm2 = (const float*)d_in[10];
    const float* Wc3 = (const float*)d_in[11];
    const float* bc3 = (const float*)d_in[12];
    const float* Wm3 = (const float*)d_in[13];
    const float* bm3 = (const float*)d_in[14];
    const float* W1 = (const float*)d_in[15];
    const float* b1 = (const float*)d_in[16];
    const float* W2 = (const float*)d_in[17];
    const float* b2 = (const float*)d_in[18];
    float* out = (float*)d_out;

    // ws layout:
    //   [0, 83886080)            X0 [B][N][160] f16      -> later yc2/x2 (67MB)
    //   [83886080, 218103808)    yc1/x1 [B][N][256] f16  -> later yc3/x3 (33.5MB)
    //   [218103808, ...)         Wfrags, parts, stats
    char* ws = (char*)d_ws;
    f16* X0 = (f16*)ws;
    f16* A1 = (f16*)(ws + 83886080);
    f16* A2 = (f16*)ws;
    f16* A3 = A1;
    size_t toff = 218103808;
    f16* Wfc1 = (f16*)(ws + toff); toff += (size_t)480 * 256 * 2;
    f16* Wfm1 = (f16*)(ws + toff); toff += (size_t)160 * 256 * 2;
    f16* Wfc2 = (f16*)(ws + toff); toff += (size_t)768 * 128 * 2;
    f16* Wfm2 = (f16*)(ws + toff); toff += (size_t)256 * 128 * 2;
    f16* Wfc3 = (f16*)(ws + toff); toff += (size_t)384 * 64 * 2;
    f16* Wfm3 = (f16*)(ws + toff); toff += (size_t)128 * 64 * 2;
    float2* part  = (float2*)(ws + toff); toff += (size_t)256 * 16 * 8;
    float2* stats = (float2*)(ws + toff);

    transpose_kernel<<<dim3(16, 5, 256), 256, 0, stream>>>(trees, X0);
    prepW_kernel<<<480 * 256 / 256, 256, 0, stream>>>(Wc1, Wfc1, 480, 256, 160, 1);
    prepW_kernel<<<160 * 256 / 256, 256, 0, stream>>>(Wm1, Wfm1, 160, 256, 160, 0);
    prepW_kernel<<<768 * 128 / 256, 256, 0, stream>>>(Wc2, Wfc2, 768, 128, 256, 1);
    prepW_kernel<<<256 * 128 / 256, 256, 0, stream>>>(Wm2, Wfm2, 256, 128, 256, 0);
    prepW_kernel<<<384 * 64 / 256, 256, 0, stream>>>(Wc3, Wfc3, 384, 64, 128, 1);
    prepW_kernel<<<128 * 64 / 256, 256, 0, stream>>>(Wm3, Wfm3, 128, 64, 128, 0);

    convA_kernel<160, 256><<<dim3(16, 256), 256, 0, stream>>>(X0, indexes, Wfc1, bc1, A1, part);
    reduce_stats_kernel<<<256, 64, 0, stream>>>(part, stats, 16, 262144.f);
    mixB_kernel<160, 256><<<dim3(16, 256), 256, 0, stream>>>(X0, Wfm1, bm1, A1, stats);

    convA_kernel<256, 128><<<dim3(16, 256), 256, 0, stream>>>(A1, indexes, Wfc2, bc2, A2, part);
    reduce_stats_kernel<<<256, 64, 0, stream>>>(part, stats, 16, 131072.f);
    mixB_kernel<256, 128><<<dim3(16, 256), 256, 0, stream>>>(A1, Wfm2, bm2, A2, stats);

    convA_kernel<128, 64><<<dim3(16, 256), 256, 0, stream>>>(A2, indexes, Wfc3, bc3, A3, part);
    reduce_stats_kernel<<<256, 64, 0, stream>>>(part, stats, 16, 65536.f);
    mixB_kernel<128, 64><<<dim3(16, 256), 256, 0, stream>>>(A2, Wfm3, bm3, A3, stats);

    final_kernel<<<256, 256, 0, stream>>>(A3, nodes, W1, b1, W2, b2, out);
}